// Round 11
// baseline (291.961 us; speedup 1.0000x reference)
//
#include <hip/hip_runtime.h>
#include <hip/hip_bf16.h>
#include <math.h>

// LoRA attention, MI355X bf16-MFMA pipeline, round 11.
// r8 template exactly (best measured: 128x128x64, 8 waves 2Mx4N, 64 KiB LDS,
// 2 blk/CU, 4-phase/2-K-step race-free stage ledger, vmcnt(2), N-marching),
// with the MFMA shape swapped 16x16x32 -> 32x32x16 (half the MFMA instructions,
// faster pipe, same LDS bytes, same VGPR budget).

typedef __attribute__((ext_vector_type(4))) float f32x4;
typedef __attribute__((ext_vector_type(16))) float f32x16;
typedef __attribute__((ext_vector_type(8))) short bf8;   // 8 x bf16
typedef __attribute__((ext_vector_type(4))) short bf4;   // 4 x bf16

__device__ __forceinline__ unsigned short f2bf(float f) {
  union { float f; unsigned u; } c; c.f = f;
  return (unsigned short)((c.u + 0x7fffu + ((c.u >> 16) & 1u)) >> 16);
}
__device__ __forceinline__ void gload16(const void* g, void* l) {
  __builtin_amdgcn_global_load_lds((const __attribute__((address_space(1))) void*)g,
                                   (__attribute__((address_space(3))) void*)l, 16, 0, 0);
}

// ---------------- cast fp32 -> bf16 ----------------
__global__ __launch_bounds__(256)
void k_cast(const float* __restrict__ x, __hip_bfloat16* __restrict__ o) {
  long i = ((long)blockIdx.x * 256 + threadIdx.x) * 8;
  float4 a = *(const float4*)&x[i];
  float4 b = *(const float4*)&x[i + 4];
  union { bf8 v; unsigned short h[8]; } u;
  u.h[0] = f2bf(a.x); u.h[1] = f2bf(a.y); u.h[2] = f2bf(a.z); u.h[3] = f2bf(a.w);
  u.h[4] = f2bf(b.x); u.h[5] = f2bf(b.y); u.h[6] = f2bf(b.z); u.h[7] = f2bf(b.w);
  *(bf8*)&o[i] = u.v;
}

// ---------------- Weff = W + B@A, concat [2304][768] bf16, + bias concat ----------------
__global__ __launch_bounds__(256)
void k_fold3(const float* __restrict__ W0, const float* __restrict__ A0, const float* __restrict__ B0,
             const float* __restrict__ W1, const float* __restrict__ A1, const float* __restrict__ B1,
             const float* __restrict__ W2, const float* __restrict__ A2, const float* __restrict__ B2,
             const float* __restrict__ bq, const float* __restrict__ bk, const float* __restrict__ bv,
             __hip_bfloat16* __restrict__ out, float* __restrict__ bcat) {
  int idx = blockIdx.x * 256 + threadIdx.x;
  if (idx < 2304)
    bcat[idx] = (idx < 768) ? bq[idx] : (idx < 1536) ? bk[idx - 768] : bv[idx - 1536];
  int t = idx / 589824, j = idx - t * 589824;
  const float* W = (t == 0) ? W0 : (t == 1) ? W1 : W2;
  const float* A = (t == 0) ? A0 : (t == 1) ? A1 : A2;
  const float* Bl = (t == 0) ? B0 : (t == 1) ? B1 : B2;
  int d = j % 768, o = j / 768;
  float acc = W[j];
  #pragma unroll
  for (int r = 0; r < 32; ++r) acc += Bl[o * 32 + r] * A[r * 768 + d];
  out[idx] = __float2bfloat16(acc);
}

// ---------------- 128x128x64 8-wave N-marching GEMM (32x32x16 MFMA) ----------------
// Out[m][n] = sum_k A[m][k] * B[n][k]
// MODE 0: PV   (A=P' ld4096, B=Vt ld8192 +z*4096, fp32 out / lsum)     MARCH=1
// MODE 1: scores (A=Q ld1536, B=A+768; P'=exp(acc*scale) + atomic lsum) MARCH=4
// MODE 3: proj (col<1536 -> bf16 [8192][1536] +bias; else Vt +bias)     MARCH=2
// Per wave: 64x32 out = 2 frags of 32x32 (acc f32x16 x2).
// Phases per K-step (r8 schedule, unchanged):
//   P0(buf0): read af(mb0) 4 + bv 4; stage A(s+1)->buf1; bar; 4 MFMA; bar
//   P1(buf0): read af(mb1) 4;        stage B(s+2)->buf0; bar; 4 MFMA; vmcnt(2); bar
//   P2/P3: same on buf1 with s+2/s+3.
template<int MODE, int MARCH>
__global__ __launch_bounds__(512, 4)
void k_gm(const __hip_bfloat16* __restrict__ Ag, const __hip_bfloat16* __restrict__ Bg,
          const float* __restrict__ bias, void* __restrict__ Og, void* __restrict__ Og2,
          float* __restrict__ lsum, float scale)
{
  __shared__ short lds[32768];   // 64 KiB: [buf2][opA/B][2half][64x64 bf16]
  constexpr int NT = (MODE == 0) ? 64 : 12;
  constexpr int S = NT * MARCH;
  const int tid = threadIdx.x, w = tid >> 6, lane = tid & 63;
  const int wm = w >> 2, wn = w & 3;
  const int ln31 = lane & 31;
  const int hi16 = (lane >> 5) << 4;    // byte offset selecting k-half within slice
  const int hi4  = (lane >> 5) << 2;    // C/D row offset

  // T1 XCD swizzle, N-fast tile mapping
  const int gy = gridDim.y;
  const int nwg = gridDim.x * gy;
  const int w0 = blockIdx.y * gridDim.x + blockIdx.x;
  const int wid = (w0 & 7) * (nwg >> 3) + (w0 >> 3);
  const long M0 = (long)(wid / gy) * 128;
  const long NG0 = (long)(wid % gy) * (128 * MARCH);

  const __hip_bfloat16 *A, *B; long lda, ldb;
  if constexpr (MODE == 0) {
    A = Ag + (long)blockIdx.z * 4096 * 4096; lda = 4096;
    B = Bg + (long)blockIdx.z * 4096;        ldb = 8192;
  } else if constexpr (MODE == 1) {
    A = Ag + (long)blockIdx.z * 4096 * 1536; B = A + 768; lda = 1536; ldb = 1536;
  } else {
    A = Ag; B = Bg; lda = 768; ldb = 768;
  }

  // staging (identical to r8): half-tile 64 rows x 64 k; T2 pre-swizzled source col
  const int srow = tid >> 3;                       // 0..63
  const int scol = (((tid & 7) ^ (srow & 7)) << 3);
  const __hip_bfloat16* pA[2] = { A + (M0 + srow) * lda + scol, A + (M0 + 64 + srow) * lda + scol };
  const __hip_bfloat16* pB[2] = { B + (NG0 + srow) * ldb + scol, B + (NG0 + 64 + srow) * ldb + scol };
  char* Lc = (char*)lds;
  const int wbyte = w * 1024;
  auto stage = [&](int op, int h, int s) {
    char* dst = Lc + (s & 1) * 32768 + op * 16384 + h * 8192 + wbyte;  // wave-uniform
    long off;
    if (op == 0) off = (long)(s % NT) * 64;
    else         off = (long)(s / NT) * 128 * ldb + (long)(s % NT) * 64;
    gload16((op ? pB[h] : pA[h]) + off, dst);
  };
  // 32x32x16 fragment reads: lane holds op[row = base + (lane&31)][k = ks*16 + (lane>>5)*8 ..+8]
  auto rdA = [&](int row, int ks, int d) -> bf8 {
    const int sb = ((ks << 5) + hi16) ^ ((row & 7) << 4);
    return *(const bf8*)(Lc + d * 32768 + row * 128 + sb);
  };
  auto rdB = [&](int row, int ks, int d) -> bf8 {
    const int sb = ((ks << 5) + hi16) ^ ((row & 7) << 4);
    return *(const bf8*)(Lc + d * 32768 + 16384 + row * 128 + sb);
  };

  f32x16 acc[2] = {};   // [m-block 0/1], each 32x32

  // per-n-tile epilogue; C/D map: col=lane&31, row=(reg&3)+8*(reg>>2)+4*(lane>>5)
  auto dump = [&](int j) {
    #pragma unroll
    for (int mb = 0; mb < 2; ++mb) {
      const long rowb = M0 + wm * 64 + mb * 32;
      if constexpr (MODE == 0) {
        float* Of = (float*)Og + (long)blockIdx.z * 4096 * 768;
        const float* lz = lsum + (long)blockIdx.z * 4096;
        const long col = NG0 + wn * 32 + ln31;
        #pragma unroll
        for (int g = 0; g < 4; ++g) {
          #pragma unroll
          for (int q = 0; q < 4; ++q) {
            const long row = rowb + g * 8 + hi4 + q;
            Of[row * 768 + col] = acc[mb][g * 4 + q] / lz[row];
          }
        }
      } else if constexpr (MODE == 1) {
        __hip_bfloat16* Ob = (__hip_bfloat16*)Og + (long)blockIdx.z * 4096 * 4096;
        float* lz = lsum + (long)blockIdx.z * 4096;
        const long col = NG0 + (long)j * 128 + wn * 32 + ln31;
        #pragma unroll
        for (int g = 0; g < 4; ++g) {
          #pragma unroll
          for (int q = 0; q < 4; ++q) {
            const long row = rowb + g * 8 + hi4 + q;
            const float e = __expf(fminf(acc[mb][g * 4 + q] * scale, 70.0f));
            *(unsigned short*)&Ob[row * 4096 + col] = f2bf(e);
            float v = e;
            v += __shfl_xor(v, 1); v += __shfl_xor(v, 2); v += __shfl_xor(v, 4);
            v += __shfl_xor(v, 8); v += __shfl_xor(v, 16);
            if (ln31 == 0) atomicAdd(&lz[row], v);
          }
        }
      } else {
        const long col = NG0 + (long)j * 128 + wn * 32 + ln31;
        const float bvl = bias[col];
        if (col < 1536) {
          __hip_bfloat16* O = (__hip_bfloat16*)Og;
          #pragma unroll
          for (int g = 0; g < 4; ++g)
            #pragma unroll
            for (int q = 0; q < 4; ++q) {
              const long row = rowb + g * 8 + hi4 + q;
              *(unsigned short*)&O[row * 1536 + col] = f2bf(acc[mb][g * 4 + q] + bvl);
            }
        } else {
          __hip_bfloat16* O2 = (__hip_bfloat16*)Og2;
          #pragma unroll
          for (int g = 0; g < 4; ++g) {
            bf4 v;
            #pragma unroll
            for (int q = 0; q < 4; ++q) v[q] = (short)f2bf(acc[mb][g * 4 + q] + bvl);
            *(bf4*)&O2[(col - 1536) * 8192 + rowb + g * 8 + hi4] = v;
          }
        }
      }
    }
    acc[0] = (f32x16)(0.f); acc[1] = (f32x16)(0.f);
  };

  // prologue (r8): B(0),A(0),B(1) staged; vmcnt(2) retires tile0
  stage(1,0,0); stage(1,1,0); stage(0,0,0); stage(0,1,0);
  stage(1,0,1); stage(1,1,1);
  asm volatile("s_waitcnt vmcnt(2)" ::: "memory");
  __builtin_amdgcn_s_barrier();
  asm volatile("" ::: "memory");

  bf8 af[4], bv[4];
  for (int s = 0; s < S; s += 2) {
    if (MARCH > 1 && s > 0 && (s % NT) == 0) dump(s / NT - 1);
    const int s1 = s + 1;
    const int s2 = (s + 2 < S) ? s + 2 : S - 1;   // clamp: rewrites identical bytes
    const int s3 = (s + 3 < S) ? s + 3 : S - 1;

    // ---- P0 (buf0, m-block 0) ----
    #pragma unroll
    for (int ks = 0; ks < 4; ++ks) af[ks] = rdA(wm * 64 + ln31, ks, 0);
    #pragma unroll
    for (int ks = 0; ks < 4; ++ks) bv[ks] = rdB(wn * 32 + ln31, ks, 0);
    stage(0,0,s1); stage(0,1,s1);
    asm volatile("" ::: "memory");
    __builtin_amdgcn_s_barrier();
    __builtin_amdgcn_s_setprio(1);
    #pragma unroll
    for (int ks = 0; ks < 4; ++ks)
      acc[0] = __builtin_amdgcn_mfma_f32_32x32x16_bf16(af[ks], bv[ks], acc[0], 0, 0, 0);
    __builtin_amdgcn_s_setprio(0);
    __builtin_amdgcn_s_barrier();
    asm volatile("" ::: "memory");

    // ---- P1 (buf0, m-block 1) ----
    #pragma unroll
    for (int ks = 0; ks < 4; ++ks) af[ks] = rdA(wm * 64 + 32 + ln31, ks, 0);
    stage(1,0,s2); stage(1,1,s2);
    asm volatile("" ::: "memory");
    __builtin_amdgcn_s_barrier();
    __builtin_amdgcn_s_setprio(1);
    #pragma unroll
    for (int ks = 0; ks < 4; ++ks)
      acc[1] = __builtin_amdgcn_mfma_f32_32x32x16_bf16(af[ks], bv[ks], acc[1], 0, 0, 0);
    __builtin_amdgcn_s_setprio(0);
    asm volatile("s_waitcnt vmcnt(2)" ::: "memory");   // A(s+1),B(s+1) landed
    __builtin_amdgcn_s_barrier();
    asm volatile("" ::: "memory");

    // ---- P2 (buf1, m-block 0) ----
    #pragma unroll
    for (int ks = 0; ks < 4; ++ks) af[ks] = rdA(wm * 64 + ln31, ks, 1);
    #pragma unroll
    for (int ks = 0; ks < 4; ++ks) bv[ks] = rdB(wn * 32 + ln31, ks, 1);
    stage(0,0,s2); stage(0,1,s2);
    asm volatile("" ::: "memory");
    __builtin_amdgcn_s_barrier();
    __builtin_amdgcn_s_setprio(1);
    #pragma unroll
    for (int ks = 0; ks < 4; ++ks)
      acc[0] = __builtin_amdgcn_mfma_f32_32x32x16_bf16(af[ks], bv[ks], acc[0], 0, 0, 0);
    __builtin_amdgcn_s_setprio(0);
    __builtin_amdgcn_s_barrier();
    asm volatile("" ::: "memory");

    // ---- P3 (buf1, m-block 1) ----
    #pragma unroll
    for (int ks = 0; ks < 4; ++ks) af[ks] = rdA(wm * 64 + 32 + ln31, ks, 1);
    stage(1,0,s3); stage(1,1,s3);
    asm volatile("" ::: "memory");
    __builtin_amdgcn_s_barrier();
    __builtin_amdgcn_s_setprio(1);
    #pragma unroll
    for (int ks = 0; ks < 4; ++ks)
      acc[1] = __builtin_amdgcn_mfma_f32_32x32x16_bf16(af[ks], bv[ks], acc[1], 0, 0, 0);
    __builtin_amdgcn_s_setprio(0);
    asm volatile("s_waitcnt vmcnt(2)" ::: "memory");   // A(s+2),B(s+2) landed
    __builtin_amdgcn_s_barrier();
    asm volatile("" ::: "memory");
  }

  dump(MARCH - 1);
}

extern "C" void kernel_launch(void* const* d_in, const int* in_sizes, int n_in,
                              void* d_out, int out_size, void* d_ws, size_t ws_size,
                              hipStream_t stream) {
  const float* x  = (const float*)d_in[0];
  const float* Wq = (const float*)d_in[1]; const float* bq = (const float*)d_in[2];
  const float* Wk = (const float*)d_in[3]; const float* bk = (const float*)d_in[4];
  const float* Wv = (const float*)d_in[5]; const float* bv = (const float*)d_in[6];
  const float* Aq = (const float*)d_in[7]; const float* Bq = (const float*)d_in[8];
  const float* Ak = (const float*)d_in[9]; const float* Bk = (const float*)d_in[10];
  const float* Av = (const float*)d_in[11]; const float* Bv = (const float*)d_in[12];

  // ws layout (bf16 elems), ~121 MB
  __hip_bfloat16* Xb   = (__hip_bfloat16*)d_ws;        // [8192][768]
  __hip_bfloat16* WeA  = Xb  + 6291456;                // [2304][768]
  __hip_bfloat16* QKb  = WeA + 1769472;                // [8192][1536] (Q 0-767, K 768-1535)
  __hip_bfloat16* Vt   = QKb + 12582912;               // [768][8192]
  __hip_bfloat16* Pb   = Vt  + 6291456;                // [2][4096][4096] unnormalized exp
  float*          bcat = (float*)(Pb + 33554432);      // [2304]
  float*          lsum = bcat + 2304;                  // [2][4096] row sums
  float* out = (float*)d_out;

  k_cast<<<3072, 256, 0, stream>>>(x, Xb);
  k_fold3<<<6912, 256, 0, stream>>>(Wq, Aq, Bq, Wk, Ak, Bk, Wv, Av, Bv,
                                    bq, bk, bv, WeA, bcat);
  hipMemsetAsync(lsum, 0, 8192 * sizeof(float), stream);

  // projections: M=8192, N=2304, K=768 (march 2)
  k_gm<3, 2><<<dim3(64, 9, 1), 512, 0, stream>>>(Xb, WeA, bcat, QKb, Vt, nullptr, 1.0f);
  // scores + exp + rowsum: per batch M=N=4096, K=768 (march 4)
  const float sc = 0.036084391824351615f;
  k_gm<1, 4><<<dim3(32, 8, 2), 512, 0, stream>>>(QKb, nullptr, nullptr, Pb, nullptr, lsum, sc);
  // PV: per batch M=4096, N=768, K=4096 (march 1); epilogue normalizes by lsum
  k_gm<0, 1><<<dim3(32, 6, 2), 512, 0, stream>>>(Pb, Vt, nullptr, out, nullptr, lsum, 1.0f);
}

// Round 12
// 238.523 us; speedup vs baseline: 1.2240x; 1.2240x over previous
//
#include <hip/hip_runtime.h>
#include <hip/hip_bf16.h>
#include <math.h>

// LoRA attention, MI355X bf16-MFMA pipeline, round 12.
// r8 template VERBATIM (best measured: 207.8 us) with one change: PV runs
// split-K2 inside the same template (NT=32, z=batch*2+split, atomicAdd of
// normalized partials into zeroed out) to fix PV's 25% residency waste
// (384 blocks vs 512 slots -> 768 half-length blocks).

typedef __attribute__((ext_vector_type(4))) float f32x4;
typedef __attribute__((ext_vector_type(8))) short bf8;   // 8 x bf16
typedef __attribute__((ext_vector_type(4))) short bf4;   // 4 x bf16

__device__ __forceinline__ unsigned short f2bf(float f) {
  union { float f; unsigned u; } c; c.f = f;
  return (unsigned short)((c.u + 0x7fffu + ((c.u >> 16) & 1u)) >> 16);
}
__device__ __forceinline__ void gload16(const void* g, void* l) {
  __builtin_amdgcn_global_load_lds((const __attribute__((address_space(1))) void*)g,
                                   (__attribute__((address_space(3))) void*)l, 16, 0, 0);
}

// ---------------- cast fp32 -> bf16 ----------------
__global__ __launch_bounds__(256)
void k_cast(const float* __restrict__ x, __hip_bfloat16* __restrict__ o) {
  long i = ((long)blockIdx.x * 256 + threadIdx.x) * 8;
  float4 a = *(const float4*)&x[i];
  float4 b = *(const float4*)&x[i + 4];
  union { bf8 v; unsigned short h[8]; } u;
  u.h[0] = f2bf(a.x); u.h[1] = f2bf(a.y); u.h[2] = f2bf(a.z); u.h[3] = f2bf(a.w);
  u.h[4] = f2bf(b.x); u.h[5] = f2bf(b.y); u.h[6] = f2bf(b.z); u.h[7] = f2bf(b.w);
  *(bf8*)&o[i] = u.v;
}

// ---------------- Weff = W + B@A, concat [2304][768] bf16, + bias concat ----------------
__global__ __launch_bounds__(256)
void k_fold3(const float* __restrict__ W0, const float* __restrict__ A0, const float* __restrict__ B0,
             const float* __restrict__ W1, const float* __restrict__ A1, const float* __restrict__ B1,
             const float* __restrict__ W2, const float* __restrict__ A2, const float* __restrict__ B2,
             const float* __restrict__ bq, const float* __restrict__ bk, const float* __restrict__ bv,
             __hip_bfloat16* __restrict__ out, float* __restrict__ bcat) {
  int idx = blockIdx.x * 256 + threadIdx.x;
  if (idx < 2304)
    bcat[idx] = (idx < 768) ? bq[idx] : (idx < 1536) ? bk[idx - 768] : bv[idx - 1536];
  int t = idx / 589824, j = idx - t * 589824;
  const float* W = (t == 0) ? W0 : (t == 1) ? W1 : W2;
  const float* A = (t == 0) ? A0 : (t == 1) ? A1 : A2;
  const float* Bl = (t == 0) ? B0 : (t == 1) ? B1 : B2;
  int d = j % 768, o = j / 768;
  float acc = W[j];
  #pragma unroll
  for (int r = 0; r < 32; ++r) acc += Bl[o * 32 + r] * A[r * 768 + d];
  out[idx] = __float2bfloat16(acc);
}

// ---------------- 128x128x64 8-wave N-marching GEMM (r8 template) ----------------
// Out[m][n] = sum_k A[m][k] * B[n][k]
// MODE 0: PV split-K2 (z=batch*2+split; A=P'+split*2048 ld4096, B=Vt+split*2048
//         ld8192; NT=32; epilogue atomicAdd(out, acc/lsum) -- out zeroed)  MARCH=1
// MODE 1: scores (A=Q ld1536, B=A+768; P'=exp(acc*scale) + atomic lsum)    MARCH=4
// MODE 3: proj (col<1536 -> bf16 [8192][1536] +bias; else Vt +bias)        MARCH=2
template<int MODE, int MARCH>
__global__ __launch_bounds__(512, 4)
void k_gm(const __hip_bfloat16* __restrict__ Ag, const __hip_bfloat16* __restrict__ Bg,
          const float* __restrict__ bias, void* __restrict__ Og, void* __restrict__ Og2,
          float* __restrict__ lsum, float scale)
{
  __shared__ short lds[32768];   // 64 KiB: [buf2][opA/B][2half][64x64 bf16]
  constexpr int NT = (MODE == 0) ? 32 : 12;
  constexpr int S = NT * MARCH;
  const int tid = threadIdx.x, w = tid >> 6, lane = tid & 63;
  const int wm = w >> 2, wn = w & 3;
  const int lnlo = lane & 15, lnhi = lane >> 4;

  // T1 XCD swizzle, N-fast tile mapping
  const int gy = gridDim.y;
  const int nwg = gridDim.x * gy;
  const int w0 = blockIdx.y * gridDim.x + blockIdx.x;
  const int wid = (w0 & 7) * (nwg >> 3) + (w0 >> 3);
  const long M0 = (long)(wid / gy) * 128;
  const long NG0 = (long)(wid % gy) * (128 * MARCH);

  const __hip_bfloat16 *A, *B; long lda, ldb;
  int batch = blockIdx.z;
  if constexpr (MODE == 0) {
    batch = blockIdx.z >> 1;
    const int split = blockIdx.z & 1;
    A = Ag + (long)batch * 4096 * 4096 + (long)split * 2048; lda = 4096;
    B = Bg + (long)batch * 4096 + (long)split * 2048;        ldb = 8192;
  } else if constexpr (MODE == 1) {
    A = Ag + (long)batch * 4096 * 1536; B = A + 768; lda = 1536; ldb = 1536;
  } else {
    A = Ag; B = Bg; lda = 768; ldb = 768;
  }

  // staging: half-tile 64 rows x 64 k = 1 gload16/thread; T2 pre-swizzled source col
  const int srow = tid >> 3;                       // 0..63
  const int scol = (((tid & 7) ^ (srow & 7)) << 3);
  const __hip_bfloat16* pA[2] = { A + (M0 + srow) * lda + scol, A + (M0 + 64 + srow) * lda + scol };
  const __hip_bfloat16* pB[2] = { B + (NG0 + srow) * ldb + scol, B + (NG0 + 64 + srow) * ldb + scol };
  char* Lc = (char*)lds;
  const int wbyte = w * 1024;
  auto stage = [&](int op, int h, int s) {         // 1 gload16/thread
    char* dst = Lc + (s & 1) * 32768 + op * 16384 + h * 8192 + wbyte;  // wave-uniform
    long off;
    if (op == 0) off = (long)(s % NT) * 64;
    else         off = (long)(s / NT) * 128 * ldb + (long)(s % NT) * 64;
    gload16((op ? pB[h] : pA[h]) + off, dst);
  };
  auto rdA = [&](int row, int k, int d) -> bf8 {   // T2-swizzled LDS read
    const int sb = ((k << 6) + (lnhi << 4)) ^ ((row & 7) << 4);
    return *(const bf8*)(Lc + d * 32768 + row * 128 + sb);
  };
  auto rdB = [&](int row, int k, int d) -> bf8 {
    const int sb = ((k << 6) + (lnhi << 4)) ^ ((row & 7) << 4);
    return *(const bf8*)(Lc + d * 32768 + 16384 + row * 128 + sb);
  };

  f32x4 acc[4][2] = {};   // wave tile 64x32: [m-frag][n-frag]

  // per-n-tile epilogue (no LDS use -> overlaps with in-flight staging)
  auto dump = [&](int j) {
    #pragma unroll
    for (int mi = 0; mi < 4; ++mi) {
      const long row = M0 + wm * 64 + mi * 16 + lnhi * 4;
      if constexpr (MODE == 0) {
        float* Of = (float*)Og + (long)batch * 4096 * 768;
        const float* lz = lsum + (long)batch * 4096;
        float linv[4];
        #pragma unroll
        for (int r = 0; r < 4; ++r) linv[r] = 1.0f / lz[row + r];
        #pragma unroll
        for (int ni = 0; ni < 2; ++ni) {
          const long col = NG0 + wn * 32 + ni * 16 + lnlo;
          #pragma unroll
          for (int r = 0; r < 4; ++r)
            atomicAdd(&Of[(row + r) * 768 + col], acc[mi][ni][r] * linv[r]);
        }
      } else if constexpr (MODE == 1) {
        __hip_bfloat16* Ob = (__hip_bfloat16*)Og + (long)batch * 4096 * 4096;
        float* lz = lsum + (long)batch * 4096;
        float rs[4] = {0.f, 0.f, 0.f, 0.f};
        #pragma unroll
        for (int ni = 0; ni < 2; ++ni) {
          const long col = NG0 + (long)j * 128 + wn * 32 + ni * 16 + lnlo;
          #pragma unroll
          for (int r = 0; r < 4; ++r) {
            const float e = __expf(fminf(acc[mi][ni][r] * scale, 70.0f));
            rs[r] += e;
            *(unsigned short*)&Ob[(row + r) * 4096 + col] = f2bf(e);
          }
        }
        #pragma unroll
        for (int r = 0; r < 4; ++r) {
          float v = rs[r];
          v += __shfl_xor(v, 1); v += __shfl_xor(v, 2);
          v += __shfl_xor(v, 4); v += __shfl_xor(v, 8);
          if (lnlo == 0) atomicAdd(&lz[row + r], v);
        }
      } else {
        #pragma unroll
        for (int ni = 0; ni < 2; ++ni) {
          const long col = NG0 + (long)j * 128 + wn * 32 + ni * 16 + lnlo;
          const float bvl = bias[col];
          if (col < 1536) {
            __hip_bfloat16* O = (__hip_bfloat16*)Og;
            #pragma unroll
            for (int r = 0; r < 4; ++r)
              *(unsigned short*)&O[(row + r) * 1536 + col] = f2bf(acc[mi][ni][r] + bvl);
          } else {
            __hip_bfloat16* O2 = (__hip_bfloat16*)Og2;
            bf4 v;
            #pragma unroll
            for (int r = 0; r < 4; ++r) v[r] = (short)f2bf(acc[mi][ni][r] + bvl);
            *(bf4*)&O2[(col - 1536) * 8192 + row] = v;
          }
        }
      }
    }
    #pragma unroll
    for (int mi = 0; mi < 4; ++mi)
      #pragma unroll
      for (int ni = 0; ni < 2; ++ni) acc[mi][ni] = (f32x4){0.f, 0.f, 0.f, 0.f};
  };

  // prologue: B(0),A(0),B(1) -> vmcnt(2) retires tile0
  stage(1,0,0); stage(1,1,0); stage(0,0,0); stage(0,1,0);
  stage(1,0,1); stage(1,1,1);
  asm volatile("s_waitcnt vmcnt(2)" ::: "memory");
  __builtin_amdgcn_s_barrier();
  asm volatile("" ::: "memory");

  bf8 af[2][2], bv[2][2];
  for (int s = 0; s < S; s += 2) {
    if (MARCH > 1 && s > 0 && (s % NT) == 0) dump(s / NT - 1);
    const int s1 = s + 1;
    const int s2 = (s + 2 < S) ? s + 2 : S - 1;   // clamp: rewrites identical bytes
    const int s3 = (s + 3 < S) ? s + 3 : S - 1;

    // ---- P0 (buf0, m-half 0) ----
    #pragma unroll
    for (int m = 0; m < 2; ++m)
      #pragma unroll
      for (int k = 0; k < 2; ++k) af[m][k] = rdA(wm * 64 + m * 16 + lnlo, k, 0);
    #pragma unroll
    for (int n = 0; n < 2; ++n)
      #pragma unroll
      for (int k = 0; k < 2; ++k) bv[n][k] = rdB(wn * 32 + n * 16 + lnlo, k, 0);
    stage(0,0,s1); stage(0,1,s1);
    asm volatile("" ::: "memory");
    __builtin_amdgcn_s_barrier();
    __builtin_amdgcn_s_setprio(1);
    #pragma unroll
    for (int m = 0; m < 2; ++m)
      #pragma unroll
      for (int n = 0; n < 2; ++n) {
        acc[m][n] = __builtin_amdgcn_mfma_f32_16x16x32_bf16(af[m][0], bv[n][0], acc[m][n], 0,0,0);
        acc[m][n] = __builtin_amdgcn_mfma_f32_16x16x32_bf16(af[m][1], bv[n][1], acc[m][n], 0,0,0);
      }
    __builtin_amdgcn_s_setprio(0);
    __builtin_amdgcn_s_barrier();
    asm volatile("" ::: "memory");

    // ---- P1 (buf0, m-half 1) ----
    #pragma unroll
    for (int m = 0; m < 2; ++m)
      #pragma unroll
      for (int k = 0; k < 2; ++k) af[m][k] = rdA(wm * 64 + 32 + m * 16 + lnlo, k, 0);
    stage(1,0,s2); stage(1,1,s2);
    asm volatile("" ::: "memory");
    __builtin_amdgcn_s_barrier();
    __builtin_amdgcn_s_setprio(1);
    #pragma unroll
    for (int m = 0; m < 2; ++m)
      #pragma unroll
      for (int n = 0; n < 2; ++n) {
        acc[2+m][n] = __builtin_amdgcn_mfma_f32_16x16x32_bf16(af[m][0], bv[n][0], acc[2+m][n], 0,0,0);
        acc[2+m][n] = __builtin_amdgcn_mfma_f32_16x16x32_bf16(af[m][1], bv[n][1], acc[2+m][n], 0,0,0);
      }
    __builtin_amdgcn_s_setprio(0);
    asm volatile("s_waitcnt vmcnt(2)" ::: "memory");   // A(s+1),B(s+1) landed
    __builtin_amdgcn_s_barrier();
    asm volatile("" ::: "memory");

    // ---- P2 (buf1, m-half 0) ----
    #pragma unroll
    for (int m = 0; m < 2; ++m)
      #pragma unroll
      for (int k = 0; k < 2; ++k) af[m][k] = rdA(wm * 64 + m * 16 + lnlo, k, 1);
    #pragma unroll
    for (int n = 0; n < 2; ++n)
      #pragma unroll
      for (int k = 0; k < 2; ++k) bv[n][k] = rdB(wn * 32 + n * 16 + lnlo, k, 1);
    stage(0,0,s2); stage(0,1,s2);
    asm volatile("" ::: "memory");
    __builtin_amdgcn_s_barrier();
    __builtin_amdgcn_s_setprio(1);
    #pragma unroll
    for (int m = 0; m < 2; ++m)
      #pragma unroll
      for (int n = 0; n < 2; ++n) {
        acc[m][n] = __builtin_amdgcn_mfma_f32_16x16x32_bf16(af[m][0], bv[n][0], acc[m][n], 0,0,0);
        acc[m][n] = __builtin_amdgcn_mfma_f32_16x16x32_bf16(af[m][1], bv[n][1], acc[m][n], 0,0,0);
      }
    __builtin_amdgcn_s_setprio(0);
    __builtin_amdgcn_s_barrier();
    asm volatile("" ::: "memory");

    // ---- P3 (buf1, m-half 1) ----
    #pragma unroll
    for (int m = 0; m < 2; ++m)
      #pragma unroll
      for (int k = 0; k < 2; ++k) af[m][k] = rdA(wm * 64 + 32 + m * 16 + lnlo, k, 1);
    stage(1,0,s3); stage(1,1,s3);
    asm volatile("" ::: "memory");
    __builtin_amdgcn_s_barrier();
    __builtin_amdgcn_s_setprio(1);
    #pragma unroll
    for (int m = 0; m < 2; ++m)
      #pragma unroll
      for (int n = 0; n < 2; ++n) {
        acc[2+m][n] = __builtin_amdgcn_mfma_f32_16x16x32_bf16(af[m][0], bv[n][0], acc[2+m][n], 0,0,0);
        acc[2+m][n] = __builtin_amdgcn_mfma_f32_16x16x32_bf16(af[m][1], bv[n][1], acc[2+m][n], 0,0,0);
      }
    __builtin_amdgcn_s_setprio(0);
    asm volatile("s_waitcnt vmcnt(2)" ::: "memory");   // A(s+2),B(s+2) landed
    __builtin_amdgcn_s_barrier();
    asm volatile("" ::: "memory");
  }

  dump(MARCH - 1);
}

extern "C" void kernel_launch(void* const* d_in, const int* in_sizes, int n_in,
                              void* d_out, int out_size, void* d_ws, size_t ws_size,
                              hipStream_t stream) {
  const float* x  = (const float*)d_in[0];
  const float* Wq = (const float*)d_in[1]; const float* bq = (const float*)d_in[2];
  const float* Wk = (const float*)d_in[3]; const float* bk = (const float*)d_in[4];
  const float* Wv = (const float*)d_in[5]; const float* bv = (const float*)d_in[6];
  const float* Aq = (const float*)d_in[7]; const float* Bq = (const float*)d_in[8];
  const float* Ak = (const float*)d_in[9]; const float* Bk = (const float*)d_in[10];
  const float* Av = (const float*)d_in[11]; const float* Bv = (const float*)d_in[12];

  // ws layout (bf16 elems), ~121 MB
  __hip_bfloat16* Xb   = (__hip_bfloat16*)d_ws;        // [8192][768]
  __hip_bfloat16* WeA  = Xb  + 6291456;                // [2304][768]
  __hip_bfloat16* QKb  = WeA + 1769472;                // [8192][1536] (Q 0-767, K 768-1535)
  __hip_bfloat16* Vt   = QKb + 12582912;               // [768][8192]
  __hip_bfloat16* Pb   = Vt  + 6291456;                // [2][4096][4096] unnormalized exp
  float*          bcat = (float*)(Pb + 33554432);      // [2304]
  float*          lsum = bcat + 2304;                  // [2][4096] row sums
  float* out = (float*)d_out;

  k_cast<<<3072, 256, 0, stream>>>(x, Xb);
  k_fold3<<<6912, 256, 0, stream>>>(Wq, Aq, Bq, Wk, Ak, Bk, Wv, Av, Bv,
                                    bq, bk, bv, WeA, bcat);
  hipMemsetAsync(lsum, 0, 8192 * sizeof(float), stream);
  hipMemsetAsync(out, 0, 2L * 4096 * 768 * sizeof(float), stream);  // split-K accum base

  // projections: M=8192, N=2304, K=768 (march 2)
  k_gm<3, 2><<<dim3(64, 9, 1), 512, 0, stream>>>(Xb, WeA, bcat, QKb, Vt, nullptr, 1.0f);
  // scores + exp + rowsum: per batch M=N=4096, K=768 (march 4)
  const float sc = 0.036084391824351615f;
  k_gm<1, 4><<<dim3(32, 8, 2), 512, 0, stream>>>(QKb, nullptr, nullptr, Pb, nullptr, lsum, sc);
  // PV: per batch M=4096, N=768, K=4096, split-K2 (z=batch*2+split), NT=32
  k_gm<0, 1><<<dim3(32, 6, 4), 512, 0, stream>>>(Pb, Vt, nullptr, out, nullptr, lsum, 1.0f);
}

// Round 13
// 192.264 us; speedup vs baseline: 1.5185x; 1.2406x over previous
//
#include <hip/hip_runtime.h>
#include <hip/hip_bf16.h>
#include <math.h>

// LoRA attention, MI355X bf16-MFMA pipeline, round 13.
// r8 template VERBATIM (best measured: 207.8 us). One change: proj marches 3
// n-tiles (grid 384 = single fully-resident round at 2 blk/CU) instead of
// march 2 (grid 576 = 512+64 two-round makespan). PV back to r8 exact.

typedef __attribute__((ext_vector_type(4))) float f32x4;
typedef __attribute__((ext_vector_type(8))) short bf8;   // 8 x bf16
typedef __attribute__((ext_vector_type(4))) short bf4;   // 4 x bf16

__device__ __forceinline__ unsigned short f2bf(float f) {
  union { float f; unsigned u; } c; c.f = f;
  return (unsigned short)((c.u + 0x7fffu + ((c.u >> 16) & 1u)) >> 16);
}
__device__ __forceinline__ void gload16(const void* g, void* l) {
  __builtin_amdgcn_global_load_lds((const __attribute__((address_space(1))) void*)g,
                                   (__attribute__((address_space(3))) void*)l, 16, 0, 0);
}

// ---------------- cast fp32 -> bf16 ----------------
__global__ __launch_bounds__(256)
void k_cast(const float* __restrict__ x, __hip_bfloat16* __restrict__ o) {
  long i = ((long)blockIdx.x * 256 + threadIdx.x) * 8;
  float4 a = *(const float4*)&x[i];
  float4 b = *(const float4*)&x[i + 4];
  union { bf8 v; unsigned short h[8]; } u;
  u.h[0] = f2bf(a.x); u.h[1] = f2bf(a.y); u.h[2] = f2bf(a.z); u.h[3] = f2bf(a.w);
  u.h[4] = f2bf(b.x); u.h[5] = f2bf(b.y); u.h[6] = f2bf(b.z); u.h[7] = f2bf(b.w);
  *(bf8*)&o[i] = u.v;
}

// ---------------- Weff = W + B@A, concat [2304][768] bf16, + bias concat ----------------
__global__ __launch_bounds__(256)
void k_fold3(const float* __restrict__ W0, const float* __restrict__ A0, const float* __restrict__ B0,
             const float* __restrict__ W1, const float* __restrict__ A1, const float* __restrict__ B1,
             const float* __restrict__ W2, const float* __restrict__ A2, const float* __restrict__ B2,
             const float* __restrict__ bq, const float* __restrict__ bk, const float* __restrict__ bv,
             __hip_bfloat16* __restrict__ out, float* __restrict__ bcat) {
  int idx = blockIdx.x * 256 + threadIdx.x;
  if (idx < 2304)
    bcat[idx] = (idx < 768) ? bq[idx] : (idx < 1536) ? bk[idx - 768] : bv[idx - 1536];
  int t = idx / 589824, j = idx - t * 589824;
  const float* W = (t == 0) ? W0 : (t == 1) ? W1 : W2;
  const float* A = (t == 0) ? A0 : (t == 1) ? A1 : A2;
  const float* Bl = (t == 0) ? B0 : (t == 1) ? B1 : B2;
  int d = j % 768, o = j / 768;
  float acc = W[j];
  #pragma unroll
  for (int r = 0; r < 32; ++r) acc += Bl[o * 32 + r] * A[r * 768 + d];
  out[idx] = __float2bfloat16(acc);
}

// ---------------- 128x128x64 8-wave N-marching GEMM (r8 template) ----------------
// Out[m][n] = sum_k A[m][k] * B[n][k]
// MODE 0: PV   (A=P' ld4096, B=Vt ld8192 +z*4096, fp32 out / lsum)     MARCH=1
// MODE 1: scores (A=Q ld1536, B=A+768; P'=exp(acc*scale) + atomic lsum) MARCH=4
// MODE 3: proj (col<1536 -> bf16 [8192][1536] +bias; else Vt +bias)     MARCH=3
template<int MODE, int MARCH>
__global__ __launch_bounds__(512, 4)
void k_gm(const __hip_bfloat16* __restrict__ Ag, const __hip_bfloat16* __restrict__ Bg,
          const float* __restrict__ bias, void* __restrict__ Og, void* __restrict__ Og2,
          float* __restrict__ lsum, float scale)
{
  __shared__ short lds[32768];   // 64 KiB: [buf2][opA/B][2half][64x64 bf16]
  constexpr int NT = (MODE == 0) ? 64 : 12;
  constexpr int S = NT * MARCH;
  const int tid = threadIdx.x, w = tid >> 6, lane = tid & 63;
  const int wm = w >> 2, wn = w & 3;
  const int lnlo = lane & 15, lnhi = lane >> 4;

  // T1 XCD swizzle, N-fast tile mapping
  const int gy = gridDim.y;
  const int nwg = gridDim.x * gy;
  const int w0 = blockIdx.y * gridDim.x + blockIdx.x;
  const int wid = (w0 & 7) * (nwg >> 3) + (w0 >> 3);
  const long M0 = (long)(wid / gy) * 128;
  const long NG0 = (long)(wid % gy) * (128 * MARCH);

  const __hip_bfloat16 *A, *B; long lda, ldb;
  if constexpr (MODE == 0) {
    A = Ag + (long)blockIdx.z * 4096 * 4096; lda = 4096;
    B = Bg + (long)blockIdx.z * 4096;        ldb = 8192;
  } else if constexpr (MODE == 1) {
    A = Ag + (long)blockIdx.z * 4096 * 1536; B = A + 768; lda = 1536; ldb = 1536;
  } else {
    A = Ag; B = Bg; lda = 768; ldb = 768;
  }

  // staging: half-tile 64 rows x 64 k = 1 gload16/thread; T2 pre-swizzled source col
  const int srow = tid >> 3;                       // 0..63
  const int scol = (((tid & 7) ^ (srow & 7)) << 3);
  const __hip_bfloat16* pA[2] = { A + (M0 + srow) * lda + scol, A + (M0 + 64 + srow) * lda + scol };
  const __hip_bfloat16* pB[2] = { B + (NG0 + srow) * ldb + scol, B + (NG0 + 64 + srow) * ldb + scol };
  char* Lc = (char*)lds;
  const int wbyte = w * 1024;
  auto stage = [&](int op, int h, int s) {         // 1 gload16/thread
    char* dst = Lc + (s & 1) * 32768 + op * 16384 + h * 8192 + wbyte;  // wave-uniform
    long off;
    if (op == 0) off = (long)(s % NT) * 64;
    else         off = (long)(s / NT) * 128 * ldb + (long)(s % NT) * 64;
    gload16((op ? pB[h] : pA[h]) + off, dst);
  };
  auto rdA = [&](int row, int k, int d) -> bf8 {   // T2-swizzled LDS read
    const int sb = ((k << 6) + (lnhi << 4)) ^ ((row & 7) << 4);
    return *(const bf8*)(Lc + d * 32768 + row * 128 + sb);
  };
  auto rdB = [&](int row, int k, int d) -> bf8 {
    const int sb = ((k << 6) + (lnhi << 4)) ^ ((row & 7) << 4);
    return *(const bf8*)(Lc + d * 32768 + 16384 + row * 128 + sb);
  };

  f32x4 acc[4][2] = {};   // wave tile 64x32: [m-frag][n-frag]

  // per-n-tile epilogue (no LDS use -> overlaps with in-flight staging)
  auto dump = [&](int j) {
    #pragma unroll
    for (int mi = 0; mi < 4; ++mi) {
      const long row = M0 + wm * 64 + mi * 16 + lnhi * 4;
      if constexpr (MODE == 0) {
        float* Of = (float*)Og + (long)blockIdx.z * 4096 * 768;
        const float* lz = lsum + (long)blockIdx.z * 4096;
        float linv[4];
        #pragma unroll
        for (int r = 0; r < 4; ++r) linv[r] = 1.0f / lz[row + r];
        #pragma unroll
        for (int ni = 0; ni < 2; ++ni) {
          const long col = NG0 + wn * 32 + ni * 16 + lnlo;
          #pragma unroll
          for (int r = 0; r < 4; ++r) Of[(row + r) * 768 + col] = acc[mi][ni][r] * linv[r];
        }
      } else if constexpr (MODE == 1) {
        __hip_bfloat16* Ob = (__hip_bfloat16*)Og + (long)blockIdx.z * 4096 * 4096;
        float* lz = lsum + (long)blockIdx.z * 4096;
        float rs[4] = {0.f, 0.f, 0.f, 0.f};
        #pragma unroll
        for (int ni = 0; ni < 2; ++ni) {
          const long col = NG0 + (long)j * 128 + wn * 32 + ni * 16 + lnlo;
          #pragma unroll
          for (int r = 0; r < 4; ++r) {
            const float e = __expf(fminf(acc[mi][ni][r] * scale, 70.0f));
            rs[r] += e;
            *(unsigned short*)&Ob[(row + r) * 4096 + col] = f2bf(e);
          }
        }
        #pragma unroll
        for (int r = 0; r < 4; ++r) {
          float v = rs[r];
          v += __shfl_xor(v, 1); v += __shfl_xor(v, 2);
          v += __shfl_xor(v, 4); v += __shfl_xor(v, 8);
          if (lnlo == 0) atomicAdd(&lz[row + r], v);
        }
      } else {
        #pragma unroll
        for (int ni = 0; ni < 2; ++ni) {
          const long col = NG0 + (long)j * 128 + wn * 32 + ni * 16 + lnlo;
          const float bvl = bias[col];
          if (col < 1536) {
            __hip_bfloat16* O = (__hip_bfloat16*)Og;
            #pragma unroll
            for (int r = 0; r < 4; ++r)
              *(unsigned short*)&O[(row + r) * 1536 + col] = f2bf(acc[mi][ni][r] + bvl);
          } else {
            __hip_bfloat16* O2 = (__hip_bfloat16*)Og2;
            bf4 v;
            #pragma unroll
            for (int r = 0; r < 4; ++r) v[r] = (short)f2bf(acc[mi][ni][r] + bvl);
            *(bf4*)&O2[(col - 1536) * 8192 + row] = v;
          }
        }
      }
    }
    #pragma unroll
    for (int mi = 0; mi < 4; ++mi)
      #pragma unroll
      for (int ni = 0; ni < 2; ++ni) acc[mi][ni] = (f32x4){0.f, 0.f, 0.f, 0.f};
  };

  // prologue: B(0),A(0),B(1) -> vmcnt(2) retires tile0
  stage(1,0,0); stage(1,1,0); stage(0,0,0); stage(0,1,0);
  stage(1,0,1); stage(1,1,1);
  asm volatile("s_waitcnt vmcnt(2)" ::: "memory");
  __builtin_amdgcn_s_barrier();
  asm volatile("" ::: "memory");

  bf8 af[2][2], bv[2][2];
  for (int s = 0; s < S; s += 2) {
    if (MARCH > 1 && s > 0 && (s % NT) == 0) dump(s / NT - 1);
    const int s1 = s + 1;
    const int s2 = (s + 2 < S) ? s + 2 : S - 1;   // clamp: rewrites identical bytes
    const int s3 = (s + 3 < S) ? s + 3 : S - 1;

    // ---- P0 (buf0, m-half 0) ----
    #pragma unroll
    for (int m = 0; m < 2; ++m)
      #pragma unroll
      for (int k = 0; k < 2; ++k) af[m][k] = rdA(wm * 64 + m * 16 + lnlo, k, 0);
    #pragma unroll
    for (int n = 0; n < 2; ++n)
      #pragma unroll
      for (int k = 0; k < 2; ++k) bv[n][k] = rdB(wn * 32 + n * 16 + lnlo, k, 0);
    stage(0,0,s1); stage(0,1,s1);
    asm volatile("" ::: "memory");
    __builtin_amdgcn_s_barrier();
    __builtin_amdgcn_s_setprio(1);
    #pragma unroll
    for (int m = 0; m < 2; ++m)
      #pragma unroll
      for (int n = 0; n < 2; ++n) {
        acc[m][n] = __builtin_amdgcn_mfma_f32_16x16x32_bf16(af[m][0], bv[n][0], acc[m][n], 0,0,0);
        acc[m][n] = __builtin_amdgcn_mfma_f32_16x16x32_bf16(af[m][1], bv[n][1], acc[m][n], 0,0,0);
      }
    __builtin_amdgcn_s_setprio(0);
    __builtin_amdgcn_s_barrier();
    asm volatile("" ::: "memory");

    // ---- P1 (buf0, m-half 1) ----
    #pragma unroll
    for (int m = 0; m < 2; ++m)
      #pragma unroll
      for (int k = 0; k < 2; ++k) af[m][k] = rdA(wm * 64 + 32 + m * 16 + lnlo, k, 0);
    stage(1,0,s2); stage(1,1,s2);
    asm volatile("" ::: "memory");
    __builtin_amdgcn_s_barrier();
    __builtin_amdgcn_s_setprio(1);
    #pragma unroll
    for (int m = 0; m < 2; ++m)
      #pragma unroll
      for (int n = 0; n < 2; ++n) {
        acc[2+m][n] = __builtin_amdgcn_mfma_f32_16x16x32_bf16(af[m][0], bv[n][0], acc[2+m][n], 0,0,0);
        acc[2+m][n] = __builtin_amdgcn_mfma_f32_16x16x32_bf16(af[m][1], bv[n][1], acc[2+m][n], 0,0,0);
      }
    __builtin_amdgcn_s_setprio(0);
    asm volatile("s_waitcnt vmcnt(2)" ::: "memory");   // A(s+1),B(s+1) landed
    __builtin_amdgcn_s_barrier();
    asm volatile("" ::: "memory");

    // ---- P2 (buf1, m-half 0) ----
    #pragma unroll
    for (int m = 0; m < 2; ++m)
      #pragma unroll
      for (int k = 0; k < 2; ++k) af[m][k] = rdA(wm * 64 + m * 16 + lnlo, k, 1);
    #pragma unroll
    for (int n = 0; n < 2; ++n)
      #pragma unroll
      for (int k = 0; k < 2; ++k) bv[n][k] = rdB(wn * 32 + n * 16 + lnlo, k, 1);
    stage(0,0,s2); stage(0,1,s2);
    asm volatile("" ::: "memory");
    __builtin_amdgcn_s_barrier();
    __builtin_amdgcn_s_setprio(1);
    #pragma unroll
    for (int m = 0; m < 2; ++m)
      #pragma unroll
      for (int n = 0; n < 2; ++n) {
        acc[m][n] = __builtin_amdgcn_mfma_f32_16x16x32_bf16(af[m][0], bv[n][0], acc[m][n], 0,0,0);
        acc[m][n] = __builtin_amdgcn_mfma_f32_16x16x32_bf16(af[m][1], bv[n][1], acc[m][n], 0,0,0);
      }
    __builtin_amdgcn_s_setprio(0);
    __builtin_amdgcn_s_barrier();
    asm volatile("" ::: "memory");

    // ---- P3 (buf1, m-half 1) ----
    #pragma unroll
    for (int m = 0; m < 2; ++m)
      #pragma unroll
      for (int k = 0; k < 2; ++k) af[m][k] = rdA(wm * 64 + 32 + m * 16 + lnlo, k, 1);
    stage(1,0,s3); stage(1,1,s3);
    asm volatile("" ::: "memory");
    __builtin_amdgcn_s_barrier();
    __builtin_amdgcn_s_setprio(1);
    #pragma unroll
    for (int m = 0; m < 2; ++m)
      #pragma unroll
      for (int n = 0; n < 2; ++n) {
        acc[2+m][n] = __builtin_amdgcn_mfma_f32_16x16x32_bf16(af[m][0], bv[n][0], acc[2+m][n], 0,0,0);
        acc[2+m][n] = __builtin_amdgcn_mfma_f32_16x16x32_bf16(af[m][1], bv[n][1], acc[2+m][n], 0,0,0);
      }
    __builtin_amdgcn_s_setprio(0);
    asm volatile("s_waitcnt vmcnt(2)" ::: "memory");   // A(s+2),B(s+2) landed
    __builtin_amdgcn_s_barrier();
    asm volatile("" ::: "memory");
  }

  dump(MARCH - 1);
}

extern "C" void kernel_launch(void* const* d_in, const int* in_sizes, int n_in,
                              void* d_out, int out_size, void* d_ws, size_t ws_size,
                              hipStream_t stream) {
  const float* x  = (const float*)d_in[0];
  const float* Wq = (const float*)d_in[1]; const float* bq = (const float*)d_in[2];
  const float* Wk = (const float*)d_in[3]; const float* bk = (const float*)d_in[4];
  const float* Wv = (const float*)d_in[5]; const float* bv = (const float*)d_in[6];
  const float* Aq = (const float*)d_in[7]; const float* Bq = (const float*)d_in[8];
  const float* Ak = (const float*)d_in[9]; const float* Bk = (const float*)d_in[10];
  const float* Av = (const float*)d_in[11]; const float* Bv = (const float*)d_in[12];

  // ws layout (bf16 elems), ~121 MB
  __hip_bfloat16* Xb   = (__hip_bfloat16*)d_ws;        // [8192][768]
  __hip_bfloat16* WeA  = Xb  + 6291456;                // [2304][768]
  __hip_bfloat16* QKb  = WeA + 1769472;                // [8192][1536] (Q 0-767, K 768-1535)
  __hip_bfloat16* Vt   = QKb + 12582912;               // [768][8192]
  __hip_bfloat16* Pb   = Vt  + 6291456;                // [2][4096][4096] unnormalized exp
  float*          bcat = (float*)(Pb + 33554432);      // [2304]
  float*          lsum = bcat + 2304;                  // [2][4096] row sums
  float* out = (float*)d_out;

  k_cast<<<3072, 256, 0, stream>>>(x, Xb);
  k_fold3<<<6912, 256, 0, stream>>>(Wq, Aq, Bq, Wk, Ak, Bk, Wv, Av, Bv,
                                    bq, bk, bv, WeA, bcat);
  hipMemsetAsync(lsum, 0, 8192 * sizeof(float), stream);

  // projections: M=8192, N=2304, K=768 (march 3 -> 384 blocks, single round)
  k_gm<3, 3><<<dim3(64, 6, 1), 512, 0, stream>>>(Xb, WeA, bcat, QKb, Vt, nullptr, 1.0f);
  // scores + exp + rowsum: per batch M=N=4096, K=768 (march 4)
  const float sc = 0.036084391824351615f;
  k_gm<1, 4><<<dim3(32, 8, 2), 512, 0, stream>>>(QKb, nullptr, nullptr, Pb, nullptr, lsum, sc);
  // PV: per batch M=4096, N=768, K=4096 (march 1); epilogue normalizes by lsum
  k_gm<0, 1><<<dim3(32, 6, 2), 512, 0, stream>>>(Pb, Vt, nullptr, out, nullptr, lsum, 1.0f);
}

// Round 14
// 191.378 us; speedup vs baseline: 1.5256x; 1.0046x over previous
//
#include <hip/hip_runtime.h>
#include <hip/hip_bf16.h>
#include <math.h>

// LoRA attention, MI355X bf16-MFMA pipeline, round 14.
// r13 verbatim (best measured: 192.3 us) with the head stage consolidated:
// cast + fold3 + bias-concat + lsum-zero in ONE kernel launch (independent
// work, previously 3 serial launches). Scores epilogue uses native exp2f.

typedef __attribute__((ext_vector_type(4))) float f32x4;
typedef __attribute__((ext_vector_type(8))) short bf8;   // 8 x bf16
typedef __attribute__((ext_vector_type(4))) short bf4;   // 4 x bf16

__device__ __forceinline__ unsigned short f2bf(float f) {
  union { float f; unsigned u; } c; c.f = f;
  return (unsigned short)((c.u + 0x7fffu + ((c.u >> 16) & 1u)) >> 16);
}
__device__ __forceinline__ void gload16(const void* g, void* l) {
  __builtin_amdgcn_global_load_lds((const __attribute__((address_space(1))) void*)g,
                                   (__attribute__((address_space(3))) void*)l, 16, 0, 0);
}

// ---------------- head: cast fp32->bf16 | Weff fold | bias concat | lsum zero ----------------
__global__ __launch_bounds__(256)
void k_head(const float* __restrict__ x, __hip_bfloat16* __restrict__ Xb,
            const float* __restrict__ W0, const float* __restrict__ A0, const float* __restrict__ B0,
            const float* __restrict__ W1, const float* __restrict__ A1, const float* __restrict__ B1,
            const float* __restrict__ W2, const float* __restrict__ A2, const float* __restrict__ B2,
            const float* __restrict__ bq, const float* __restrict__ bk, const float* __restrict__ bv,
            __hip_bfloat16* __restrict__ WeA, float* __restrict__ bcat, float* __restrict__ lsum) {
  const int b = blockIdx.x;
  if (b < 3072) {                       // ---- cast: 8192x768 fp32 -> bf16, 8/thread ----
    long i = ((long)b * 256 + threadIdx.x) * 8;
    float4 a = *(const float4*)&x[i];
    float4 c = *(const float4*)&x[i + 4];
    union { bf8 v; unsigned short h[8]; } u;
    u.h[0] = f2bf(a.x); u.h[1] = f2bf(a.y); u.h[2] = f2bf(a.z); u.h[3] = f2bf(a.w);
    u.h[4] = f2bf(c.x); u.h[5] = f2bf(c.y); u.h[6] = f2bf(c.z); u.h[7] = f2bf(c.w);
    *(bf8*)&Xb[i] = u.v;
  } else {                              // ---- fold: Weff = W + B@A, concat [2304][768] ----
    int idx = (b - 3072) * 256 + threadIdx.x;
    if (idx < 2304)
      bcat[idx] = (idx < 768) ? bq[idx] : (idx < 1536) ? bk[idx - 768] : bv[idx - 1536];
    if (idx < 8192) lsum[idx] = 0.0f;
    int t = idx / 589824, j = idx - t * 589824;
    const float* W = (t == 0) ? W0 : (t == 1) ? W1 : W2;
    const float* A = (t == 0) ? A0 : (t == 1) ? A1 : A2;
    const float* Bl = (t == 0) ? B0 : (t == 1) ? B1 : B2;
    int d = j % 768, o = j / 768;
    float acc = W[j];
    #pragma unroll
    for (int r = 0; r < 32; ++r) acc += Bl[o * 32 + r] * A[r * 768 + d];
    WeA[idx] = __float2bfloat16(acc);
  }
}

// ---------------- 128x128x64 8-wave N-marching GEMM (r8 template) ----------------
// Out[m][n] = sum_k A[m][k] * B[n][k]
// MODE 0: PV   (A=P' ld4096, B=Vt ld8192 +z*4096, fp32 out / lsum)     MARCH=1
// MODE 1: scores (A=Q ld1536, B=A+768; P'=exp2(acc*scale2) + atomic lsum) MARCH=4
// MODE 3: proj (col<1536 -> bf16 [8192][1536] +bias; else Vt +bias)     MARCH=3
template<int MODE, int MARCH>
__global__ __launch_bounds__(512, 4)
void k_gm(const __hip_bfloat16* __restrict__ Ag, const __hip_bfloat16* __restrict__ Bg,
          const float* __restrict__ bias, void* __restrict__ Og, void* __restrict__ Og2,
          float* __restrict__ lsum, float scale)
{
  __shared__ short lds[32768];   // 64 KiB: [buf2][opA/B][2half][64x64 bf16]
  constexpr int NT = (MODE == 0) ? 64 : 12;
  constexpr int S = NT * MARCH;
  const int tid = threadIdx.x, w = tid >> 6, lane = tid & 63;
  const int wm = w >> 2, wn = w & 3;
  const int lnlo = lane & 15, lnhi = lane >> 4;

  // T1 XCD swizzle, N-fast tile mapping
  const int gy = gridDim.y;
  const int nwg = gridDim.x * gy;
  const int w0 = blockIdx.y * gridDim.x + blockIdx.x;
  const int wid = (w0 & 7) * (nwg >> 3) + (w0 >> 3);
  const long M0 = (long)(wid / gy) * 128;
  const long NG0 = (long)(wid % gy) * (128 * MARCH);

  const __hip_bfloat16 *A, *B; long lda, ldb;
  if constexpr (MODE == 0) {
    A = Ag + (long)blockIdx.z * 4096 * 4096; lda = 4096;
    B = Bg + (long)blockIdx.z * 4096;        ldb = 8192;
  } else if constexpr (MODE == 1) {
    A = Ag + (long)blockIdx.z * 4096 * 1536; B = A + 768; lda = 1536; ldb = 1536;
  } else {
    A = Ag; B = Bg; lda = 768; ldb = 768;
  }

  // staging: half-tile 64 rows x 64 k = 1 gload16/thread; T2 pre-swizzled source col
  const int srow = tid >> 3;                       // 0..63
  const int scol = (((tid & 7) ^ (srow & 7)) << 3);
  const __hip_bfloat16* pA[2] = { A + (M0 + srow) * lda + scol, A + (M0 + 64 + srow) * lda + scol };
  const __hip_bfloat16* pB[2] = { B + (NG0 + srow) * ldb + scol, B + (NG0 + 64 + srow) * ldb + scol };
  char* Lc = (char*)lds;
  const int wbyte = w * 1024;
  auto stage = [&](int op, int h, int s) {         // 1 gload16/thread
    char* dst = Lc + (s & 1) * 32768 + op * 16384 + h * 8192 + wbyte;  // wave-uniform
    long off;
    if (op == 0) off = (long)(s % NT) * 64;
    else         off = (long)(s / NT) * 128 * ldb + (long)(s % NT) * 64;
    gload16((op ? pB[h] : pA[h]) + off, dst);
  };
  auto rdA = [&](int row, int k, int d) -> bf8 {   // T2-swizzled LDS read
    const int sb = ((k << 6) + (lnhi << 4)) ^ ((row & 7) << 4);
    return *(const bf8*)(Lc + d * 32768 + row * 128 + sb);
  };
  auto rdB = [&](int row, int k, int d) -> bf8 {
    const int sb = ((k << 6) + (lnhi << 4)) ^ ((row & 7) << 4);
    return *(const bf8*)(Lc + d * 32768 + 16384 + row * 128 + sb);
  };

  f32x4 acc[4][2] = {};   // wave tile 64x32: [m-frag][n-frag]

  // per-n-tile epilogue (no LDS use -> overlaps with in-flight staging)
  auto dump = [&](int j) {
    #pragma unroll
    for (int mi = 0; mi < 4; ++mi) {
      const long row = M0 + wm * 64 + mi * 16 + lnhi * 4;
      if constexpr (MODE == 0) {
        float* Of = (float*)Og + (long)blockIdx.z * 4096 * 768;
        const float* lz = lsum + (long)blockIdx.z * 4096;
        float linv[4];
        #pragma unroll
        for (int r = 0; r < 4; ++r) linv[r] = 1.0f / lz[row + r];
        #pragma unroll
        for (int ni = 0; ni < 2; ++ni) {
          const long col = NG0 + wn * 32 + ni * 16 + lnlo;
          #pragma unroll
          for (int r = 0; r < 4; ++r) Of[(row + r) * 768 + col] = acc[mi][ni][r] * linv[r];
        }
      } else if constexpr (MODE == 1) {
        __hip_bfloat16* Ob = (__hip_bfloat16*)Og + (long)blockIdx.z * 4096 * 4096;
        float* lz = lsum + (long)blockIdx.z * 4096;
        float rs[4] = {0.f, 0.f, 0.f, 0.f};
        #pragma unroll
        for (int ni = 0; ni < 2; ++ni) {
          const long col = NG0 + (long)j * 128 + wn * 32 + ni * 16 + lnlo;
          #pragma unroll
          for (int r = 0; r < 4; ++r) {
            const float e = exp2f(fminf(acc[mi][ni][r] * scale, 101.0f));  // scale has log2e folded
            rs[r] += e;
            *(unsigned short*)&Ob[(row + r) * 4096 + col] = f2bf(e);
          }
        }
        #pragma unroll
        for (int r = 0; r < 4; ++r) {
          float v = rs[r];
          v += __shfl_xor(v, 1); v += __shfl_xor(v, 2);
          v += __shfl_xor(v, 4); v += __shfl_xor(v, 8);
          if (lnlo == 0) atomicAdd(&lz[row + r], v);
        }
      } else {
        #pragma unroll
        for (int ni = 0; ni < 2; ++ni) {
          const long col = NG0 + (long)j * 128 + wn * 32 + ni * 16 + lnlo;
          const float bvl = bias[col];
          if (col < 1536) {
            __hip_bfloat16* O = (__hip_bfloat16*)Og;
            #pragma unroll
            for (int r = 0; r < 4; ++r)
              *(unsigned short*)&O[(row + r) * 1536 + col] = f2bf(acc[mi][ni][r] + bvl);
          } else {
            __hip_bfloat16* O2 = (__hip_bfloat16*)Og2;
            bf4 v;
            #pragma unroll
            for (int r = 0; r < 4; ++r) v[r] = (short)f2bf(acc[mi][ni][r] + bvl);
            *(bf4*)&O2[(col - 1536) * 8192 + row] = v;
          }
        }
      }
    }
    #pragma unroll
    for (int mi = 0; mi < 4; ++mi)
      #pragma unroll
      for (int ni = 0; ni < 2; ++ni) acc[mi][ni] = (f32x4){0.f, 0.f, 0.f, 0.f};
  };

  // prologue: B(0),A(0),B(1) -> vmcnt(2) retires tile0
  stage(1,0,0); stage(1,1,0); stage(0,0,0); stage(0,1,0);
  stage(1,0,1); stage(1,1,1);
  asm volatile("s_waitcnt vmcnt(2)" ::: "memory");
  __builtin_amdgcn_s_barrier();
  asm volatile("" ::: "memory");

  bf8 af[2][2], bv[2][2];
  for (int s = 0; s < S; s += 2) {
    if (MARCH > 1 && s > 0 && (s % NT) == 0) dump(s / NT - 1);
    const int s1 = s + 1;
    const int s2 = (s + 2 < S) ? s + 2 : S - 1;   // clamp: rewrites identical bytes
    const int s3 = (s + 3 < S) ? s + 3 : S - 1;

    // ---- P0 (buf0, m-half 0) ----
    #pragma unroll
    for (int m = 0; m < 2; ++m)
      #pragma unroll
      for (int k = 0; k < 2; ++k) af[m][k] = rdA(wm * 64 + m * 16 + lnlo, k, 0);
    #pragma unroll
    for (int n = 0; n < 2; ++n)
      #pragma unroll
      for (int k = 0; k < 2; ++k) bv[n][k] = rdB(wn * 32 + n * 16 + lnlo, k, 0);
    stage(0,0,s1); stage(0,1,s1);
    asm volatile("" ::: "memory");
    __builtin_amdgcn_s_barrier();
    __builtin_amdgcn_s_setprio(1);
    #pragma unroll
    for (int m = 0; m < 2; ++m)
      #pragma unroll
      for (int n = 0; n < 2; ++n) {
        acc[m][n] = __builtin_amdgcn_mfma_f32_16x16x32_bf16(af[m][0], bv[n][0], acc[m][n], 0,0,0);
        acc[m][n] = __builtin_amdgcn_mfma_f32_16x16x32_bf16(af[m][1], bv[n][1], acc[m][n], 0,0,0);
      }
    __builtin_amdgcn_s_setprio(0);
    __builtin_amdgcn_s_barrier();
    asm volatile("" ::: "memory");

    // ---- P1 (buf0, m-half 1) ----
    #pragma unroll
    for (int m = 0; m < 2; ++m)
      #pragma unroll
      for (int k = 0; k < 2; ++k) af[m][k] = rdA(wm * 64 + 32 + m * 16 + lnlo, k, 0);
    stage(1,0,s2); stage(1,1,s2);
    asm volatile("" ::: "memory");
    __builtin_amdgcn_s_barrier();
    __builtin_amdgcn_s_setprio(1);
    #pragma unroll
    for (int m = 0; m < 2; ++m)
      #pragma unroll
      for (int n = 0; n < 2; ++n) {
        acc[2+m][n] = __builtin_amdgcn_mfma_f32_16x16x32_bf16(af[m][0], bv[n][0], acc[2+m][n], 0,0,0);
        acc[2+m][n] = __builtin_amdgcn_mfma_f32_16x16x32_bf16(af[m][1], bv[n][1], acc[2+m][n], 0,0,0);
      }
    __builtin_amdgcn_s_setprio(0);
    asm volatile("s_waitcnt vmcnt(2)" ::: "memory");   // A(s+1),B(s+1) landed
    __builtin_amdgcn_s_barrier();
    asm volatile("" ::: "memory");

    // ---- P2 (buf1, m-half 0) ----
    #pragma unroll
    for (int m = 0; m < 2; ++m)
      #pragma unroll
      for (int k = 0; k < 2; ++k) af[m][k] = rdA(wm * 64 + m * 16 + lnlo, k, 1);
    #pragma unroll
    for (int n = 0; n < 2; ++n)
      #pragma unroll
      for (int k = 0; k < 2; ++k) bv[n][k] = rdB(wn * 32 + n * 16 + lnlo, k, 1);
    stage(0,0,s2); stage(0,1,s2);
    asm volatile("" ::: "memory");
    __builtin_amdgcn_s_barrier();
    __builtin_amdgcn_s_setprio(1);
    #pragma unroll
    for (int m = 0; m < 2; ++m)
      #pragma unroll
      for (int n = 0; n < 2; ++n) {
        acc[m][n] = __builtin_amdgcn_mfma_f32_16x16x32_bf16(af[m][0], bv[n][0], acc[m][n], 0,0,0);
        acc[m][n] = __builtin_amdgcn_mfma_f32_16x16x32_bf16(af[m][1], bv[n][1], acc[m][n], 0,0,0);
      }
    __builtin_amdgcn_s_setprio(0);
    __builtin_amdgcn_s_barrier();
    asm volatile("" ::: "memory");

    // ---- P3 (buf1, m-half 1) ----
    #pragma unroll
    for (int m = 0; m < 2; ++m)
      #pragma unroll
      for (int k = 0; k < 2; ++k) af[m][k] = rdA(wm * 64 + 32 + m * 16 + lnlo, k, 1);
    stage(1,0,s3); stage(1,1,s3);
    asm volatile("" ::: "memory");
    __builtin_amdgcn_s_barrier();
    __builtin_amdgcn_s_setprio(1);
    #pragma unroll
    for (int m = 0; m < 2; ++m)
      #pragma unroll
      for (int n = 0; n < 2; ++n) {
        acc[2+m][n] = __builtin_amdgcn_mfma_f32_16x16x32_bf16(af[m][0], bv[n][0], acc[2+m][n], 0,0,0);
        acc[2+m][n] = __builtin_amdgcn_mfma_f32_16x16x32_bf16(af[m][1], bv[n][1], acc[2+m][n], 0,0,0);
      }
    __builtin_amdgcn_s_setprio(0);
    asm volatile("s_waitcnt vmcnt(2)" ::: "memory");   // A(s+2),B(s+2) landed
    __builtin_amdgcn_s_barrier();
    asm volatile("" ::: "memory");
  }

  dump(MARCH - 1);
}

extern "C" void kernel_launch(void* const* d_in, const int* in_sizes, int n_in,
                              void* d_out, int out_size, void* d_ws, size_t ws_size,
                              hipStream_t stream) {
  const float* x  = (const float*)d_in[0];
  const float* Wq = (const float*)d_in[1]; const float* bq = (const float*)d_in[2];
  const float* Wk = (const float*)d_in[3]; const float* bk = (const float*)d_in[4];
  const float* Wv = (const float*)d_in[5]; const float* bv = (const float*)d_in[6];
  const float* Aq = (const float*)d_in[7]; const float* Bq = (const float*)d_in[8];
  const float* Ak = (const float*)d_in[9]; const float* Bk = (const float*)d_in[10];
  const float* Av = (const float*)d_in[11]; const float* Bv = (const float*)d_in[12];

  // ws layout (bf16 elems), ~121 MB
  __hip_bfloat16* Xb   = (__hip_bfloat16*)d_ws;        // [8192][768]
  __hip_bfloat16* WeA  = Xb  + 6291456;                // [2304][768]
  __hip_bfloat16* QKb  = WeA + 1769472;                // [8192][1536] (Q 0-767, K 768-1535)
  __hip_bfloat16* Vt   = QKb + 12582912;               // [768][8192]
  __hip_bfloat16* Pb   = Vt  + 6291456;                // [2][4096][4096] unnormalized exp
  float*          bcat = (float*)(Pb + 33554432);      // [2304]
  float*          lsum = bcat + 2304;                  // [2][4096] row sums
  float* out = (float*)d_out;

  // head: cast (blocks 0-3071) + fold/bias/lsum-zero (blocks 3072-9983)
  k_head<<<9984, 256, 0, stream>>>(x, Xb, Wq, Aq, Bq, Wk, Ak, Bk, Wv, Av, Bv,
                                   bq, bk, bv, WeA, bcat, lsum);

  // projections: M=8192, N=2304, K=768 (march 3 -> 384 blocks, single round)
  k_gm<3, 3><<<dim3(64, 6, 1), 512, 0, stream>>>(Xb, WeA, bcat, QKb, Vt, nullptr, 1.0f);
  // scores + exp + rowsum: per batch M=N=4096, K=768 (march 4); scale·log2e folded
  const float sc2 = 0.036084391824351615f * 1.4426950408889634f;
  k_gm<1, 4><<<dim3(32, 8, 2), 512, 0, stream>>>(QKb, nullptr, nullptr, Pb, nullptr, lsum, sc2);
  // PV: per batch M=4096, N=768, K=4096 (march 1); epilogue normalizes by lsum
  k_gm<0, 1><<<dim3(32, 6, 2), 512, 0, stream>>>(Pb, Vt, nullptr, out, nullptr, lsum, 1.0f);
}